// Round 5
// baseline (347.871 us; speedup 1.0000x reference)
//
#include <hip/hip_runtime.h>
#include <hip/hip_bf16.h>
#include <math.h>

#define NBLK 16
#define KD 32
#define NDIM 512        // NBLK*KD
#define INDIM 64
#define DT_C 0.05f
#define TAU_EPS_C 1e-6f
#define MROWS 16        // batch rows per tile
#define WGSIZE 1024     // 16 waves; wave j owns block j
#define LSTRIDE 520     // bf16 elems per row (16B-aligned rows)
#define WSTRIDE 260     // word (u32) stride

// Packed k-interleaved layout: value at original col nt*16+l15 sits at
// position p = 2*l15+nt; B-frags use the same k-permutation (MFMA invariant).

typedef __attribute__((ext_vector_type(8))) short bf16x8;
typedef __attribute__((ext_vector_type(4))) float f32x4;

#define MFMA16(a,b,c) __builtin_amdgcn_mfma_f32_16x16x32_bf16((a),(b),(c),0,0,0)

__device__ __forceinline__ float fast_tanh(float x){
    float e = __expf(2.0f * x);
    return 1.0f - 2.0f / (e + 1.0f);
}
__device__ __forceinline__ float bf2f(unsigned short u){
    unsigned int x = ((unsigned int)u) << 16;
    return *reinterpret_cast<float*>(&x);
}
// cheap pack: round-half-away (<=0.5 ulp) + byte-perm; 3 VALU inst total
__device__ __forceinline__ unsigned int pack_bf2_fast(float a, float b){
    unsigned int ua = __float_as_uint(a) + 0x8000u;
    unsigned int ub = __float_as_uint(b) + 0x8000u;
    return __builtin_amdgcn_perm(ua, ub, 0x03020706);
}
__device__ __forceinline__ unsigned short f2bf_rha(float f){
    return (unsigned short)((__float_as_uint(f) + 0x8000u) >> 16);
}
__device__ __forceinline__ unsigned short f2bf(float f){
    __hip_bfloat16 h = __float2bfloat16(f);   // RNE (setup paths only)
    return *reinterpret_cast<unsigned short*>(&h);
}

// B-frag with permuted k: frag elem i at pos p=quad*8+i -> original k=((p&1)<<4)|(p>>1)
__device__ __forceinline__ bf16x8 load_bfrag_perm(const float* __restrict__ W,
                                                  int l15, int quad, int nt){
    bf16x8 r;
    #pragma unroll
    for (int i = 0; i < 8; ++i){
        int p  = quad*8 + i;
        int kk = ((p & 1) << 4) | (p >> 1);
        r[i] = (short)f2bf(W[(size_t)(nt*16 + l15)*KD + kk]);
    }
    return r;
}

__global__ __launch_bounds__(WGSIZE, 4)
void ltcn_mfma_kernel(const float* __restrict__ y_in,
                      const float* __restrict__ u_t,
                      const float* __restrict__ W_in,
                      const float* __restrict__ b_in,
                      const float* __restrict__ W_fwd,
                      const float* __restrict__ b_fwd,
                      const float* __restrict__ W_rec,
                      const float* __restrict__ b_rec,
                      const float* __restrict__ E_l,
                      const float* __restrict__ E_l_r,
                      const float* __restrict__ tau_raw,
                      const int* __restrict__ n_steps_p,
                      float* __restrict__ y_out,
                      int batch)
{
    __shared__ __align__(16) unsigned short Ybuf0[MROWS * LSTRIDE];
    __shared__ __align__(16) unsigned short Ybuf1[MROWS * LSTRIDE];
    __shared__ __align__(16) char NetRaw[MROWS * LSTRIDE * 2];  // Net; pre-loop: WinT+Ubuf alias

    unsigned short* Net  = (unsigned short*)NetRaw;
    unsigned int*   NetW = (unsigned int*)NetRaw;
    float*          WinT = (float*)NetRaw;              // 8 KB  [i][l]
    float*          Ubuf = (float*)(NetRaw + 8192);     // 4 KB  [b][i]

    const int tid  = threadIdx.x;
    const int j    = tid >> 6;
    const int lane = tid & 63;
    const int quad = lane >> 4;
    const int l15  = lane & 15;
    const int ns   = n_steps_p[0];

    const float* Wr = W_rec + (size_t)j * KD * KD;
    const float* Wf = W_fwd + (size_t)((j > 0) ? (j-1) : 0) * KD * KD;
    const float* Ee = E_l   + (size_t)j * KD * KD;
    const float* Er = E_l_r + (size_t)j * KD * KD;

    bf16x8 Brec[2], Bfwd[2], BEl[2], BElr[2];
    f32x4  cinitR[2], cinitF[2];
    float  invtau2[2];
    #pragma unroll
    for (int nt = 0; nt < 2; ++nt){
        Brec[nt] = load_bfrag_perm(Wr, l15, quad, nt);
        Bfwd[nt] = load_bfrag_perm(Wf, l15, quad, nt);
        BEl[nt]  = load_bfrag_perm(Ee, l15, quad, nt);
        BElr[nt] = load_bfrag_perm(Er, l15, quad, nt);
        int l = nt*16 + l15;
        float br = b_rec[j*KD + l];
        float bf = (j > 0) ? b_fwd[(j-1)*KD + l] : 0.f;
        cinitR[nt] = (f32x4){br, br, br, br};
        cinitF[nt] = (f32x4){bf, bf, bf, bf};
        float tr = tau_raw[j*KD + l];
        float sp = fmaxf(tr, 0.f) + log1pf(__expf(-fabsf(tr)));
        invtau2[nt] = 1.0f / (sp + TAU_EPS_C);
    }
    const float bin_s = b_in[tid & (KD-1)];
    const f32x4 zero = {0.f, 0.f, 0.f, 0.f};

    const int tiles = batch / MROWS;
    const int wword = j*16 + l15;               // D-pos word col within a row
    const int aoff  = l15*LSTRIDE + j*KD;       // A-frag b16 row base

    for (int t = blockIdx.x; t < tiles; t += gridDim.x){
        const int row0 = t * MROWS;

        // ---- load y -> regs (fp32, D positions) + packed bf16 into Ybuf0 ----
        float yv[2][4];
        #pragma unroll
        for (int r = 0; r < 4; ++r){
            int rr = quad*4 + r;
            const float* yr = y_in + (size_t)(row0 + rr)*NDIM + j*KD;
            float v0 = yr[l15], v1 = yr[16 + l15];
            yv[0][r] = v0; yv[1][r] = v1;
            ((unsigned int*)Ybuf0)[rr*WSTRIDE + wword] = pack_bf2_fast(v0, v1);
        }
        // ---- stage WinT + Ubuf (aliased into Net region) ----
        for (int idx = tid; idx < KD*INDIM; idx += WGSIZE){
            int l = idx >> 6, i = idx & 63;
            WinT[i*KD + l] = W_in[idx];
        }
        for (int idx = tid; idx < MROWS*INDIM; idx += WGSIZE)
            Ubuf[idx] = u_t[(size_t)row0*INDIM + idx];
        __syncthreads();   // BAR1: staging + Ybuf0 visible

        // ---- net0 (step-invariant) -> Ybuf1 block-0 cols, packed D-pos ----
        if (tid < MROWS * KD){
            int b = tid >> 5, l = tid & 31;
            const float* ur = &Ubuf[b*INDIM];
            float a0 = 0.f, a1 = 0.f;
            #pragma unroll
            for (int i = 0; i < INDIM; i += 2){
                a0 = fmaf(ur[i],   WinT[i*KD + l],     a0);
                a1 = fmaf(ur[i+1], WinT[(i+1)*KD + l], a1);
            }
            float n0 = fast_tanh(a0 + a1 + bin_s);
            Ybuf1[b*LSTRIDE + 2*(l & 15) + (l >> 4)] = f2bf_rha(n0);
        }
        __syncthreads();   // BAR2: net0 visible; Net region now free for step use

        // wave 0 extracts its step-invariant state (registers; Ybuf1 gets overwritten)
        bf16x8 AO0 = {0,0,0,0,0,0,0,0};
        float base0[2][4];
        if (j == 0){
            AO0 = *(const bf16x8*)&Ybuf1[l15*LSTRIDE + quad*8];
            #pragma unroll
            for (int r = 0; r < 4; ++r){
                unsigned int w = ((const unsigned int*)Ybuf1)[(quad*4 + r)*WSTRIDE + l15];
                base0[0][r] = invtau2[0] + fabsf(bf2f((unsigned short)(w & 0xFFFF)));
                base0[1][r] = invtau2[1] + fabsf(bf2f((unsigned short)(w >> 16)));
            }
        }

        int cur = 0;
        for (int s = 0; s < ns; ++s){
            const unsigned short* Yr  = cur ? Ybuf1 : Ybuf0;
            unsigned int*         YwW = (unsigned int*)(cur ? Ybuf0 : Ybuf1);

            // ---- phase A: nets (reads Yr only) ----
            bf16x8 Ar = *(const bf16x8*)&Yr[aoff + quad*8];
            f32x4 aR0 = MFMA16(Ar, Brec[0], cinitR[0]);
            f32x4 aR1 = MFMA16(Ar, Brec[1], cinitR[1]);

            float d[2][4];
            bf16x8 AOf;
            if (j > 0){
                bf16x8 Af = *(const bf16x8*)&Yr[aoff - KD + quad*8];
                f32x4 aF0 = MFMA16(Af, Bfwd[0], cinitF[0]);
                f32x4 aF1 = MFMA16(Af, Bfwd[1], cinitF[1]);
                #pragma unroll
                for (int r = 0; r < 4; ++r){
                    float nf0 = fast_tanh(aF0[r]);
                    float nf1 = fast_tanh(aF1[r]);
                    d[0][r] = invtau2[0] + fabsf(nf0);
                    d[1][r] = invtau2[1] + fabsf(nf1);
                    NetW[(quad*4 + r)*WSTRIDE + wword] = pack_bf2_fast(nf0, nf1);
                }
                __builtin_amdgcn_wave_barrier();    // writes before read (same wave, in-order DS)
                AOf = *(const bf16x8*)&Net[aoff + quad*8];
                __builtin_amdgcn_wave_barrier();    // read before netR overwrite
            } else {
                #pragma unroll
                for (int r = 0; r < 4; ++r){ d[0][r] = base0[0][r]; d[1][r] = base0[1][r]; }
                AOf = AO0;
            }

            #pragma unroll
            for (int r = 0; r < 4; ++r){
                float nr0 = fast_tanh(aR0[r]);
                float nr1 = fast_tanh(aR1[r]);
                d[0][r] += fabsf(nr0);
                d[1][r] += fabsf(nr1);
                NetW[(quad*4 + r)*WSTRIDE + wword] = pack_bf2_fast(nr0, nr1);
            }
            __builtin_amdgcn_wave_barrier();
            bf16x8 ARf = *(const bf16x8*)&Net[aoff + quad*8];
            __builtin_amdgcn_wave_barrier();

            // ---- phase B: block-diagonal projections + update (intra-wave) ----
            f32x4 o0 = MFMA16(ARf, BElr[0], zero);
            o0 = MFMA16(AOf, BEl[0], o0);
            f32x4 o1 = MFMA16(ARf, BElr[1], zero);
            o1 = MFMA16(AOf, BEl[1], o1);

            const bool wr = (s + 1 < ns);
            #pragma unroll
            for (int r = 0; r < 4; ++r){
                float y0 = yv[0][r], y1 = yv[1][r];
                float yn0 = fmaf(DT_C, fmaf(-y0, d[0][r], o0[r]), y0);
                float yn1 = fmaf(DT_C, fmaf(-y1, d[1][r], o1[r]), y1);
                yv[0][r] = yn0; yv[1][r] = yn1;
                if (wr) YwW[(quad*4 + r)*WSTRIDE + wword] = pack_bf2_fast(yn0, yn1);
            }
            __syncthreads();   // the single per-step barrier: Yw visible for next step
            cur ^= 1;
        }

        // ---- store y from registers ----
        #pragma unroll
        for (int r = 0; r < 4; ++r){
            float* yo = y_out + (size_t)(row0 + quad*4 + r)*NDIM + j*KD;
            yo[l15]      = yv[0][r];
            yo[16 + l15] = yv[1][r];
        }
    }
}

extern "C" void kernel_launch(void* const* d_in, const int* in_sizes, int n_in,
                              void* d_out, int out_size, void* d_ws, size_t ws_size,
                              hipStream_t stream) {
    const float* y       = (const float*)d_in[0];
    const float* u_t     = (const float*)d_in[1];
    const float* W_in    = (const float*)d_in[2];
    const float* b_in    = (const float*)d_in[3];
    const float* W_fwd   = (const float*)d_in[4];
    const float* b_fwd   = (const float*)d_in[5];
    const float* W_rec   = (const float*)d_in[6];
    const float* b_rec   = (const float*)d_in[7];
    const float* E_l     = (const float*)d_in[8];
    const float* E_l_r   = (const float*)d_in[9];
    const float* tau_raw = (const float*)d_in[10];
    const int*   n_steps = (const int*)d_in[11];
    float* out = (float*)d_out;

    const int batch = in_sizes[0] / NDIM;
    // grid=512: 2 WGs/CU co-resident (VGPR=64 -> 8 waves/SIMD, LDS 49KB*2 <= 160KB).
    // One WG's compute covers the other's barrier drains / LDS latency.
    const int grid  = 512;

    hipLaunchKernelGGL(ltcn_mfma_kernel, dim3(grid), dim3(WGSIZE), 0, stream,
                       y, u_t, W_in, b_in, W_fwd, b_fwd, W_rec, b_rec,
                       E_l, E_l_r, tau_raw, n_steps, out, batch);
}

// Round 6
// 307.381 us; speedup vs baseline: 1.1317x; 1.1317x over previous
//
#include <hip/hip_runtime.h>
#include <hip/hip_bf16.h>
#include <math.h>

#define NBLK 16
#define KD 32
#define NDIM 512        // NBLK*KD
#define INDIM 64
#define DT_C 0.05f
#define TAU_EPS_C 1e-6f
#define MROWS 16        // batch rows per tile (MFMA N dim, lane = batch row)
#define WGSIZE 1024     // 16 waves; wave j owns block j

// Transposed-layout design:
//   netT[l'][b] = MFMA(A = W-half (m=l'), B = yT (n=b)).  D: lane&15 = b,
//   row l' = f*16 + quad*4 + reg.  The D layout and the B layout coincide
//   in-lane under k-permutation pi(q*8+i) = q*4+(i&3)+((i&4)?16:0), applied
//   identically to the weight A-frags at setup.  So D -> next B is a pure
//   in-lane bf16 pack: no LDS, no cross-lane ops.  Only the fwd coupling
//   (wave j needs y_{j-1}) goes through LDS: 1 write + 1 read + 1 barrier
//   per step, stride-1 b128 (conflict-free).

typedef __attribute__((ext_vector_type(8))) short bf16x8;         // MFMA A/B frag
typedef __attribute__((ext_vector_type(4))) float f32x4;          // MFMA C/D frag
typedef __attribute__((ext_vector_type(4))) unsigned int u32x4;   // 16B LDS slot

#define MFMA16(a,b,c) __builtin_amdgcn_mfma_f32_16x16x32_bf16((a),(b),(c),0,0,0)

__device__ __forceinline__ float fast_tanh(float x){
    float e = __expf(2.0f * x);
    return 1.0f - 2.0f / (e + 1.0f);
}
// cheap pack: round-half-away (<=0.5 ulp) + byte-perm; 3 VALU inst per pair
__device__ __forceinline__ unsigned int pack_bf2_fast(float a, float b){
    unsigned int ua = __float_as_uint(a) + 0x8000u;
    unsigned int ub = __float_as_uint(b) + 0x8000u;
    return __builtin_amdgcn_perm(ua, ub, 0x03020706);  // lo16=a.hi16, hi16=b.hi16
}
__device__ __forceinline__ unsigned short f2bf(float f){
    __hip_bfloat16 h = __float2bfloat16(f);   // RNE (setup paths only)
    return *reinterpret_cast<unsigned short*>(&h);
}

union FragU { bf16x8 h; u32x4 u; };

__device__ __forceinline__ bf16x8 pack8_fast(const float* a, const float* b){
    FragU z;
    z.u.x = pack_bf2_fast(a[0], a[1]);
    z.u.y = pack_bf2_fast(a[2], a[3]);
    z.u.z = pack_bf2_fast(b[0], b[1]);
    z.u.w = pack_bf2_fast(b[2], b[3]);
    return z.h;
}
__device__ __forceinline__ bf16x8 pack8_rne(f32x4 a, f32x4 b){
    bf16x8 r;
    r[0]=(short)f2bf(a[0]); r[1]=(short)f2bf(a[1]); r[2]=(short)f2bf(a[2]); r[3]=(short)f2bf(a[3]);
    r[4]=(short)f2bf(b[0]); r[5]=(short)f2bf(b[1]); r[6]=(short)f2bf(b[2]); r[7]=(short)f2bf(b[3]);
    return r;
}
// Weight A-frag under pi: element i (quad q) = Wrow[q*4 + (i&3) + ((i&4)?16:0)]
// -> two contiguous float4 loads per frag.
__device__ __forceinline__ bf16x8 afrag_pi(const float* __restrict__ Wrow, int q){
    f32x4 lo = *(const f32x4*)(Wrow + q*4);
    f32x4 hi = *(const f32x4*)(Wrow + 16 + q*4);
    return pack8_rne(lo, hi);
}

__global__ __launch_bounds__(WGSIZE, 4)
void ltcn_kernel(const float* __restrict__ y_in,
                 const float* __restrict__ u_t,
                 const float* __restrict__ W_in,
                 const float* __restrict__ b_in,
                 const float* __restrict__ W_fwd,
                 const float* __restrict__ b_fwd,
                 const float* __restrict__ W_rec,
                 const float* __restrict__ b_rec,
                 const float* __restrict__ E_l,
                 const float* __restrict__ E_l_r,
                 const float* __restrict__ tau_raw,
                 const int* __restrict__ n_steps_p,
                 float* __restrict__ y_out,
                 int batch)
{
    // y-exchange buffers: [pingpong][wave j][lane] 16B slots, stride-1 per wave
    __shared__ u32x4 Ylds[2 * NBLK * 64];   // 32 KB

    const int tid  = threadIdx.x;
    const int j    = tid >> 6;       // wave = block index
    const int lane = tid & 63;
    const int q    = lane >> 4;      // quad
    const int b15  = lane & 15;      // A-ops: row m (= l'); B/D-ops: batch col b
    const int ns   = n_steps_p[0];

    // ---- setup: weight A-frags (pi-permuted) + bias/invtau D-frags ----
    const float* Wr = W_rec + (size_t)j * KD * KD;
    const float* Wf = W_fwd + (size_t)((j > 0) ? (j-1) : 0) * KD * KD;
    const float* Ee = E_l   + (size_t)j * KD * KD;
    const float* Er = E_l_r + (size_t)j * KD * KD;

    bf16x8 Arec[2], Afwd[2], AEl[2], AElr[2];
    f32x4  cR[2], cF[2];
    float  itau[2][4];
    #pragma unroll
    for (int f = 0; f < 2; ++f){
        const int row = f*16 + b15;          // l' row for A-frags
        Arec[f] = afrag_pi(Wr + row*KD, q);
        Afwd[f] = afrag_pi(Wf + row*KD, q);
        AEl[f]  = afrag_pi(Ee + row*KD, q);
        AElr[f] = afrag_pi(Er + row*KD, q);
        #pragma unroll
        for (int r = 0; r < 4; ++r){
            const int lp = f*16 + q*4 + r;   // l' at D position (f, r)
            cR[f][r] = b_rec[j*KD + lp];
            cF[f][r] = (j > 0) ? b_fwd[(j-1)*KD + lp] : 0.f;
            float tr = tau_raw[j*KD + lp];
            float sp = fmaxf(tr, 0.f) + log1pf(__expf(-fabsf(tr)));
            itau[f][r] = 1.0f / (sp + TAU_EPS_C);
        }
    }
    const f32x4 zero = {0.f, 0.f, 0.f, 0.f};
    const int tiles = batch / MROWS;

    for (int t = blockIdx.x; t < tiles; t += gridDim.x){
        const int row0 = t * MROWS;

        // ---- load y into registers at D positions (lane b15 = batch row) ----
        float yv[2][4];
        #pragma unroll
        for (int f = 0; f < 2; ++f){
            f32x4 tmp = *(const f32x4*)&y_in[(size_t)(row0 + b15)*NDIM + j*KD + f*16 + q*4];
            #pragma unroll
            for (int r = 0; r < 4; ++r) yv[f][r] = tmp[r];
        }

        // ---- wave 0: net0 via MFMA (step-invariant), all in registers ----
        bf16x8 AO0 = {0,0,0,0,0,0,0,0};
        float dec0[2][4];
        if (j == 0){
            f32x4 acc[2];
            #pragma unroll
            for (int f = 0; f < 2; ++f)
            #pragma unroll
            for (int r = 0; r < 4; ++r) acc[f][r] = b_in[f*16 + q*4 + r];
            #pragma unroll
            for (int c = 0; c < 2; ++c){          // K=64 in two 32-chunks (identity perm)
                const float* up = &u_t[(size_t)(row0 + b15)*INDIM + c*32 + q*8];
                bf16x8 uB = pack8_rne(*(const f32x4*)up, *(const f32x4*)(up + 4));
                #pragma unroll
                for (int f = 0; f < 2; ++f){
                    const float* wp = &W_in[(size_t)(f*16 + b15)*INDIM + c*32 + q*8];
                    bf16x8 wA = pack8_rne(*(const f32x4*)wp, *(const f32x4*)(wp + 4));
                    acc[f] = MFMA16(wA, uB, acc[f]);
                }
            }
            float n0[2][4];
            #pragma unroll
            for (int f = 0; f < 2; ++f)
            #pragma unroll
            for (int r = 0; r < 4; ++r){
                float v = fast_tanh(acc[f][r]);
                n0[f][r] = v;
                dec0[f][r] = itau[f][r] + fabsf(v);
            }
            AO0 = pack8_fast(n0[0], n0[1]);
        }

        int cur = 0;
        for (int s = 0; s < ns; ++s){
            // own y as B-frag (in-lane pack; also the value published to wave j+1)
            bf16x8 yB = pack8_fast(yv[0], yv[1]);
            FragU yu; yu.h = yB;
            Ylds[cur*(NBLK*64) + j*64 + lane] = yu.u;
            __syncthreads();   // the single per-step barrier

            // ---- fwd net (needs y_{j-1}) ----
            bf16x8 AO; float dec[2][4];
            if (j > 0){
                FragU pv; pv.u = Ylds[cur*(NBLK*64) + (j-1)*64 + lane];
                f32x4 a0 = MFMA16(Afwd[0], pv.h, cF[0]);
                f32x4 a1 = MFMA16(Afwd[1], pv.h, cF[1]);
                float nf[2][4];
                #pragma unroll
                for (int r = 0; r < 4; ++r){
                    nf[0][r] = fast_tanh(a0[r]);
                    nf[1][r] = fast_tanh(a1[r]);
                    dec[0][r] = itau[0][r] + fabsf(nf[0][r]);
                    dec[1][r] = itau[1][r] + fabsf(nf[1][r]);
                }
                AO = pack8_fast(nf[0], nf[1]);
            } else {
                AO = AO0;
                #pragma unroll
                for (int r = 0; r < 4; ++r){ dec[0][r] = dec0[0][r]; dec[1][r] = dec0[1][r]; }
            }

            // ---- rec net (register-fed) ----
            f32x4 g0 = MFMA16(Arec[0], yB, cR[0]);
            f32x4 g1 = MFMA16(Arec[1], yB, cR[1]);
            float nr[2][4];
            #pragma unroll
            for (int r = 0; r < 4; ++r){
                nr[0][r] = fast_tanh(g0[r]);
                nr[1][r] = fast_tanh(g1[r]);
                dec[0][r] += fabsf(nr[0][r]);
                dec[1][r] += fabsf(nr[1][r]);
            }
            bf16x8 AR = pack8_fast(nr[0], nr[1]);

            // ---- block-diagonal projections + update (all registers) ----
            f32x4 o0 = MFMA16(AEl[0], AO, MFMA16(AElr[0], AR, zero));
            f32x4 o1 = MFMA16(AEl[1], AO, MFMA16(AElr[1], AR, zero));
            #pragma unroll
            for (int r = 0; r < 4; ++r){
                yv[0][r] = fmaf(DT_C, fmaf(-yv[0][r], dec[0][r], o0[r]), yv[0][r]);
                yv[1][r] = fmaf(DT_C, fmaf(-yv[1][r], dec[1][r], o1[r]), yv[1][r]);
            }
            cur ^= 1;
        }

        // ---- store y from registers ----
        #pragma unroll
        for (int f = 0; f < 2; ++f){
            f32x4 sv = {yv[f][0], yv[f][1], yv[f][2], yv[f][3]};
            *(f32x4*)&y_out[(size_t)(row0 + b15)*NDIM + j*KD + f*16 + q*4] = sv;
        }
    }
}

extern "C" void kernel_launch(void* const* d_in, const int* in_sizes, int n_in,
                              void* d_out, int out_size, void* d_ws, size_t ws_size,
                              hipStream_t stream) {
    const float* y       = (const float*)d_in[0];
    const float* u_t     = (const float*)d_in[1];
    const float* W_in    = (const float*)d_in[2];
    const float* b_in    = (const float*)d_in[3];
    const float* W_fwd   = (const float*)d_in[4];
    const float* b_fwd   = (const float*)d_in[5];
    const float* W_rec   = (const float*)d_in[6];
    const float* b_rec   = (const float*)d_in[7];
    const float* E_l     = (const float*)d_in[8];
    const float* E_l_r   = (const float*)d_in[9];
    const float* tau_raw = (const float*)d_in[10];
    const int*   n_steps = (const int*)d_in[11];
    float* out = (float*)d_out;

    const int batch = in_sizes[0] / NDIM;
    const int grid  = 256;   // 1 WG/CU (register-bound at 16 waves/CU); 8 tiles/WG

    hipLaunchKernelGGL(ltcn_kernel, dim3(grid), dim3(WGSIZE), 0, stream,
                       y, u_t, W_in, b_in, W_fwd, b_fwd, W_rec, b_rec,
                       E_l, E_l_r, tau_raw, n_steps, out, batch);
}

// Round 7
// 297.348 us; speedup vs baseline: 1.1699x; 1.0337x over previous
//
#include <hip/hip_runtime.h>
#include <hip/hip_bf16.h>
#include <math.h>

#define NBLK 16
#define KD 32
#define NDIM 512        // NBLK*KD
#define INDIM 64
#define DT_C 0.05f
#define TAU_EPS_C 1e-6f
#define MROWS 16        // batch rows per tile
#define WGSIZE 1024     // 16 waves; wave j owns block j

// Transposed-layout design (round 6, verified): netT = MFMA(A=W, B=yT).
// D-layout == B-layout in-lane under k-permutation pi(q*8+i)=q*4+(i&3)+((i&4)?16:0),
// applied to weight A-frags at setup. D -> next B is a pure in-lane pack.
// Round 7: (a) tanh without the IEEE fdiv sequence (exp2 + v_rcp, 5 inst);
// (b) two independent batch tiles per wave (ILP) — occupancy is register-pinned
// at 16 waves/CU, so latency hiding must come from within the wave.

typedef __attribute__((ext_vector_type(8))) short bf16x8;         // MFMA A/B frag
typedef __attribute__((ext_vector_type(4))) float f32x4;          // MFMA C/D frag
typedef __attribute__((ext_vector_type(4))) unsigned int u32x4;   // 16B LDS slot

#define MFMA16(a,b,c) __builtin_amdgcn_mfma_f32_16x16x32_bf16((a),(b),(c),0,0,0)

// tanh = 1 - 2/(exp2(x*2log2e)+1): mul, exp, add, rcp, fma — no v_div_* sequence
__device__ __forceinline__ float fast_tanh(float x){
    float e = __builtin_amdgcn_exp2f(x * 2.885390081777927f);  // 2*log2(e)
    float r = __builtin_amdgcn_rcpf(e + 1.0f);
    return fmaf(-2.0f, r, 1.0f);
}
// cheap pack: round-half-away (<=0.5 ulp) + byte-perm
__device__ __forceinline__ unsigned int pack_bf2_fast(float a, float b){
    unsigned int ua = __float_as_uint(a) + 0x8000u;
    unsigned int ub = __float_as_uint(b) + 0x8000u;
    return __builtin_amdgcn_perm(ua, ub, 0x03020706);  // lo16=a.hi16, hi16=b.hi16
}
__device__ __forceinline__ unsigned short f2bf(float f){
    __hip_bfloat16 h = __float2bfloat16(f);   // RNE (setup only)
    return *reinterpret_cast<unsigned short*>(&h);
}

union FragU { bf16x8 h; u32x4 u; };

__device__ __forceinline__ bf16x8 pack8_fast(const float* a, const float* b){
    FragU z;
    z.u.x = pack_bf2_fast(a[0], a[1]);
    z.u.y = pack_bf2_fast(a[2], a[3]);
    z.u.z = pack_bf2_fast(b[0], b[1]);
    z.u.w = pack_bf2_fast(b[2], b[3]);
    return z.h;
}
__device__ __forceinline__ bf16x8 pack8_rne(f32x4 a, f32x4 b){
    bf16x8 r;
    r[0]=(short)f2bf(a[0]); r[1]=(short)f2bf(a[1]); r[2]=(short)f2bf(a[2]); r[3]=(short)f2bf(a[3]);
    r[4]=(short)f2bf(b[0]); r[5]=(short)f2bf(b[1]); r[6]=(short)f2bf(b[2]); r[7]=(short)f2bf(b[3]);
    return r;
}
// Weight A-frag under pi: two contiguous float4 loads per frag
__device__ __forceinline__ bf16x8 afrag_pi(const float* __restrict__ Wrow, int q){
    f32x4 lo = *(const f32x4*)(Wrow + q*4);
    f32x4 hi = *(const f32x4*)(Wrow + 16 + q*4);
    return pack8_rne(lo, hi);
}

__global__ __launch_bounds__(WGSIZE, 4)
void ltcn_kernel(const float* __restrict__ y_in,
                 const float* __restrict__ u_t,
                 const float* __restrict__ W_in,
                 const float* __restrict__ b_in,
                 const float* __restrict__ W_fwd,
                 const float* __restrict__ b_fwd,
                 const float* __restrict__ W_rec,
                 const float* __restrict__ b_rec,
                 const float* __restrict__ E_l,
                 const float* __restrict__ E_l_r,
                 const float* __restrict__ tau_raw,
                 const int* __restrict__ n_steps_p,
                 float* __restrict__ y_out,
                 int batch)
{
    // [pingpong][tile][wave*64+lane] 16B slots — 64 KB, stride-1 (conflict-free)
    __shared__ u32x4 Ylds[2][2][NBLK * 64];

    const int tid  = threadIdx.x;
    const int j    = tid >> 6;
    const int lane = tid & 63;
    const int q    = lane >> 4;
    const int b15  = lane & 15;
    const int ns   = n_steps_p[0];

    // ---- setup: pi-permuted weight A-frags + bias/invtau at D positions ----
    const float* Wr = W_rec + (size_t)j * KD * KD;
    const float* Wf = W_fwd + (size_t)((j > 0) ? (j-1) : 0) * KD * KD;
    const float* Ee = E_l   + (size_t)j * KD * KD;
    const float* Er = E_l_r + (size_t)j * KD * KD;

    bf16x8 Arec[2], Afwd[2], AEl[2], AElr[2];
    f32x4  cR[2], cF[2];
    float  itau[2][4];
    #pragma unroll
    for (int f = 0; f < 2; ++f){
        const int row = f*16 + b15;
        Arec[f] = afrag_pi(Wr + row*KD, q);
        Afwd[f] = afrag_pi(Wf + row*KD, q);
        AEl[f]  = afrag_pi(Ee + row*KD, q);
        AElr[f] = afrag_pi(Er + row*KD, q);
        #pragma unroll
        for (int r = 0; r < 4; ++r){
            const int lp = f*16 + q*4 + r;
            cR[f][r] = b_rec[j*KD + lp];
            cF[f][r] = (j > 0) ? b_fwd[(j-1)*KD + lp] : 0.f;
            float tr = tau_raw[j*KD + lp];
            float sp = fmaxf(tr, 0.f) + log1pf(__expf(-fabsf(tr)));
            itau[f][r] = 1.0f / (sp + TAU_EPS_C);
        }
    }
    const f32x4 zero = {0.f, 0.f, 0.f, 0.f};
    const int pairs = (batch / MROWS) / 2;

    int cur = 0;   // continuous ping-pong across tile-pairs (no parity race)

    for (int p = blockIdx.x; p < pairs; p += gridDim.x){
        const int row0A = (2*p)     * MROWS;
        const int row0B = (2*p + 1) * MROWS;

        // ---- load y (fp32, D positions) for both tiles ----
        float yv[2][2][4];
        #pragma unroll
        for (int f = 0; f < 2; ++f){
            f32x4 ta = *(const f32x4*)&y_in[(size_t)(row0A + b15)*NDIM + j*KD + f*16 + q*4];
            f32x4 tb = *(const f32x4*)&y_in[(size_t)(row0B + b15)*NDIM + j*KD + f*16 + q*4];
            #pragma unroll
            for (int r = 0; r < 4; ++r){ yv[0][f][r] = ta[r]; yv[1][f][r] = tb[r]; }
        }

        // ---- wave 0: net0 via MFMA for both tiles (step-invariant) ----
        bf16x8 AO0[2] = {{0,0,0,0,0,0,0,0},{0,0,0,0,0,0,0,0}};
        if (j == 0){
            #pragma unroll
            for (int u = 0; u < 2; ++u){
                const int r0 = u ? row0B : row0A;
                f32x4 acc[2];
                #pragma unroll
                for (int f = 0; f < 2; ++f)
                #pragma unroll
                for (int r = 0; r < 4; ++r) acc[f][r] = b_in[f*16 + q*4 + r];
                #pragma unroll
                for (int c = 0; c < 2; ++c){
                    const float* up = &u_t[(size_t)(r0 + b15)*INDIM + c*32 + q*8];
                    bf16x8 uB = pack8_rne(*(const f32x4*)up, *(const f32x4*)(up + 4));
                    #pragma unroll
                    for (int f = 0; f < 2; ++f){
                        const float* wp = &W_in[(size_t)(f*16 + b15)*INDIM + c*32 + q*8];
                        bf16x8 wA = pack8_rne(*(const f32x4*)wp, *(const f32x4*)(wp + 4));
                        acc[f] = MFMA16(wA, uB, acc[f]);
                    }
                }
                float n0[2][4];
                #pragma unroll
                for (int f = 0; f < 2; ++f)
                #pragma unroll
                for (int r = 0; r < 4; ++r) n0[f][r] = fast_tanh(acc[f][r]);
                AO0[u] = pack8_fast(n0[0], n0[1]);
            }
        }

        for (int s = 0; s < ns; ++s){
            // publish own y slices (B-frag pack, also kept in regs for rec net)
            bf16x8 yB[2];
            #pragma unroll
            for (int u = 0; u < 2; ++u){
                yB[u] = pack8_fast(yv[u][0], yv[u][1]);
                FragU w; w.h = yB[u];
                Ylds[cur][u][j*64 + lane] = w.u;
            }
            __syncthreads();   // single per-step barrier

            // ---- fwd nets (need y_{j-1}) ----
            float dec[2][2][4];
            bf16x8 AO[2];
            if (j > 0){
                #pragma unroll
                for (int u = 0; u < 2; ++u){
                    FragU pv; pv.u = Ylds[cur][u][(j-1)*64 + lane];
                    f32x4 a0 = MFMA16(Afwd[0], pv.h, cF[0]);
                    f32x4 a1 = MFMA16(Afwd[1], pv.h, cF[1]);
                    float nf[2][4];
                    #pragma unroll
                    for (int r = 0; r < 4; ++r){
                        nf[0][r] = fast_tanh(a0[r]);
                        nf[1][r] = fast_tanh(a1[r]);
                        dec[u][0][r] = itau[0][r] + fabsf(nf[0][r]);
                        dec[u][1][r] = itau[1][r] + fabsf(nf[1][r]);
                    }
                    AO[u] = pack8_fast(nf[0], nf[1]);
                }
            } else {
                // recompute dec from packed AO0 (cheap; keeps 16 VGPRs free)
                #pragma unroll
                for (int u = 0; u < 2; ++u){
                    AO[u] = AO0[u];
                    FragU w; w.h = AO0[u];
                    unsigned int ws[4] = {w.u.x, w.u.y, w.u.z, w.u.w};
                    #pragma unroll
                    for (int f = 0; f < 2; ++f)
                    #pragma unroll
                    for (int r = 0; r < 4; ++r){
                        unsigned int word = ws[f*2 + (r >> 1)];
                        unsigned int bits = (r & 1) ? (word & 0xFFFF0000u) : (word << 16);
                        dec[u][f][r] = itau[f][r] + fabsf(__uint_as_float(bits));
                    }
                }
            }

            // ---- rec nets + block-diagonal projections + update ----
            #pragma unroll
            for (int u = 0; u < 2; ++u){
                f32x4 g0 = MFMA16(Arec[0], yB[u], cR[0]);
                f32x4 g1 = MFMA16(Arec[1], yB[u], cR[1]);
                float nr[2][4];
                #pragma unroll
                for (int r = 0; r < 4; ++r){
                    nr[0][r] = fast_tanh(g0[r]);
                    nr[1][r] = fast_tanh(g1[r]);
                    dec[u][0][r] += fabsf(nr[0][r]);
                    dec[u][1][r] += fabsf(nr[1][r]);
                }
                bf16x8 AR = pack8_fast(nr[0], nr[1]);

                f32x4 o0 = MFMA16(AEl[0], AO[u], MFMA16(AElr[0], AR, zero));
                f32x4 o1 = MFMA16(AEl[1], AO[u], MFMA16(AElr[1], AR, zero));
                #pragma unroll
                for (int r = 0; r < 4; ++r){
                    yv[u][0][r] = fmaf(DT_C, fmaf(-yv[u][0][r], dec[u][0][r], o0[r]), yv[u][0][r]);
                    yv[u][1][r] = fmaf(DT_C, fmaf(-yv[u][1][r], dec[u][1][r], o1[r]), yv[u][1][r]);
                }
            }
            cur ^= 1;
        }

        // ---- store y for both tiles ----
        #pragma unroll
        for (int f = 0; f < 2; ++f){
            f32x4 sa = {yv[0][f][0], yv[0][f][1], yv[0][f][2], yv[0][f][3]};
            f32x4 sb = {yv[1][f][0], yv[1][f][1], yv[1][f][2], yv[1][f][3]};
            *(f32x4*)&y_out[(size_t)(row0A + b15)*NDIM + j*KD + f*16 + q*4] = sa;
            *(f32x4*)&y_out[(size_t)(row0B + b15)*NDIM + j*KD + f*16 + q*4] = sb;
        }
    }
}

extern "C" void kernel_launch(void* const* d_in, const int* in_sizes, int n_in,
                              void* d_out, int out_size, void* d_ws, size_t ws_size,
                              hipStream_t stream) {
    const float* y       = (const float*)d_in[0];
    const float* u_t     = (const float*)d_in[1];
    const float* W_in    = (const float*)d_in[2];
    const float* b_in    = (const float*)d_in[3];
    const float* W_fwd   = (const float*)d_in[4];
    const float* b_fwd   = (const float*)d_in[5];
    const float* W_rec   = (const float*)d_in[6];
    const float* b_rec   = (const float*)d_in[7];
    const float* E_l     = (const float*)d_in[8];
    const float* E_l_r   = (const float*)d_in[9];
    const float* tau_raw = (const float*)d_in[10];
    const int*   n_steps = (const int*)d_in[11];
    float* out = (float*)d_out;

    const int batch = in_sizes[0] / NDIM;
    const int grid  = 256;   // 1 WG/CU (register-pinned 16 waves/CU); 4 tile-pairs/WG

    hipLaunchKernelGGL(ltcn_kernel, dim3(grid), dim3(WGSIZE), 0, stream,
                       y, u_t, W_in, b_in, W_fwd, b_fwd, W_rec, b_rec,
                       E_l, E_l_r, tau_raw, n_steps, out, batch);
}